// Round 25
// baseline (46.058 us; speedup 1.0000x reference)
//
#include <hip/hip_runtime.h>
#include <math.h>

// FlowLevel: DIM=2, half=1 -> per-layer coupling depends on scalar v = z_b.
// t(v) and u(v) (pre-sigmoid) are piecewise-LINEAR in v (ReLU MLP).
// Tabulate (t, dt/dv, u, du/dv) per node; apply uses the NEAREST node's
// tangent line (exact unless a kink falls in the half-cell).
//
// v22: r24's transpose-free prep was WRONG (read fc2_w[j*128+t] = w_{k=j,j=t},
// the transpose -- r7 bug class). Restore the correct LDS transpose, and
// parallelize the real serial core instead: 4 groups x 128 lanes; group g
// computes its prefix-p0 starting state directly (contribution_j(p0) =
// [g_j<0](g_j,b_j) + [rank_j<p0](sGs_j,sBs_j); reduces to old base at p0=0)
// then sweeps only 32 serial steps. table/apply byte-identical to r23.

constexpr int kDepth = 10;
constexpr int kWidth = 128;
constexpr float kVMin = -24.0f;
constexpr float kVMax =  24.0f;

// ---------------- prep: per-layer kink sort + 4-way parallel prefix sweep ----------------
__global__ __launch_bounds__(512) void prep_kernel(
    const float* __restrict__ an_scale, const float* __restrict__ an_bias,
    const float* __restrict__ conv_w,
    const float* __restrict__ fc1_w, const float* __restrict__ fc1_b,
    const float* __restrict__ an1_scale, const float* __restrict__ an1_bias,
    const float* __restrict__ fc2_w, const float* __restrict__ fc2_b,
    const float* __restrict__ an2_scale, const float* __restrict__ an2_bias,
    const float* __restrict__ fc3_b, const float* __restrict__ lsf,
    float* __restrict__ meta, float* __restrict__ kv,
    float* __restrict__ CG, float* __restrict__ CB)
{
  __shared__ float sWT[128 * 129];           // transposed weights [j][k], padded
  __shared__ float sVs[128], sG[128], sB[128];
  __shared__ float sGs[128], sBs[128];       // sig*g, sig*b (sweep deltas)
  __shared__ int   sOrd[128], sRank[128];

  const int l = blockIdx.x;                  // layer
  const int t = threadIdx.x;                 // 0..511
  const float* wl = fc2_w + (size_t)l * kWidth * kWidth;

  // transpose fc2_w into sWT[j][k] -- all 512 threads, coalesced reads
#pragma unroll 8
  for (int fi = t; fi < 128 * 128; fi += 512) {
    const int k = fi >> 7, j = fi & 127;
    sWT[j * 129 + k] = wl[fi];               // sWT[j][k] = w_kj
  }

  // per-j gate params and kink position
  if (t < 128) {
    const float s1 = an1_scale[l*kWidth + t];
    const float g = fc1_w[l*kWidth + t] / s1;
    const float b = (fc1_b[l*kWidth + t] - an1_bias[l*kWidth + t]) / s1;
    float vs, sg;
    if (g > 0.0f)      { vs = -b / g; sg =  1.0f; }
    else if (g < 0.0f) { vs = -b / g; sg = -1.0f; }
    else               { vs = (b > 0.0f) ? -1e30f : 1e30f; sg = (b > 0.0f) ? 1.0f : 0.0f; }
    sG[t] = g; sB[t] = b; sVs[t] = vs;
    sGs[t] = sg * g; sBs[t] = sg * b;
  }
  __syncthreads();

  // stable rank sort by kink position (t<128); record both order and rank
  if (t < 128) {
    const float my = sVs[t];
    int r = 0;
    const float4* vs4 = (const float4*)sVs;
#pragma unroll
    for (int i4 = 0; i4 < 32; ++i4) {
      float4 o = vs4[i4];
      const int ib = i4 * 4;
      r += (o.x < my) || (o.x == my && ib + 0 < t);
      r += (o.y < my) || (o.y == my && ib + 1 < t);
      r += (o.z < my) || (o.z == my && ib + 2 < t);
      r += (o.w < my) || (o.w == my && ib + 3 < t);
    }
    sOrd[r] = t;
    sRank[t] = r;
  }
  __syncthreads();

  if (t < 128) kv[l*128 + t] = sVs[sOrd[t]];

  // ---- group phase: group g handles prefix rows p0..p0+31 ----
  const int g  = t >> 7;                     // 0..3
  const int k  = t & 127;                    // owned output column
  const int p0 = g * 32;

  // starting state at prefix p0, computed directly:
  // contribution_j = [g_j<0](g_j,b_j) + [rank_j<p0](sGs_j,sBs_j)
  float cg = 0.0f;
  float cb = fc2_b[l*kWidth + k] - an2_bias[l*kWidth + k];
#pragma unroll 8
  for (int j = 0; j < 128; ++j) {
    const float w  = sWT[j * 129 + k];       // conflict-free (uniform j)
    const float gj = sG[j];
    float ca = (gj < 0.0f) ? gj    : 0.0f;
    float cc = (gj < 0.0f) ? sB[j] : 0.0f;
    if (sRank[j] < p0) { ca += sGs[j]; cc += sBs[j]; }
    cg = fmaf(ca, w, cg);
    cb = fmaf(cc, w, cb);
  }

  // sweep 32 steps in 4 chunks of 8 (LDS reads pipelined within chunk)
  const size_t base = (size_t)l * 129 * 128;
#pragma unroll 1
  for (int c = 0; c < 4; ++c) {
    const int pp = p0 + c * 8;
    const int j0 = sOrd[pp + 0], j1 = sOrd[pp + 1];
    const int j2 = sOrd[pp + 2], j3 = sOrd[pp + 3];
    const int j4 = sOrd[pp + 4], j5 = sOrd[pp + 5];
    const int j6 = sOrd[pp + 6], j7 = sOrd[pp + 7];
    const float w0 = sWT[j0 * 129 + k], w1 = sWT[j1 * 129 + k];
    const float w2 = sWT[j2 * 129 + k], w3 = sWT[j3 * 129 + k];
    const float w4 = sWT[j4 * 129 + k], w5 = sWT[j5 * 129 + k];
    const float w6 = sWT[j6 * 129 + k], w7 = sWT[j7 * 129 + k];
    const float g0 = sGs[j0], b0 = sBs[j0];
    const float g1 = sGs[j1], b1 = sBs[j1];
    const float g2 = sGs[j2], b2 = sBs[j2];
    const float g3 = sGs[j3], b3 = sBs[j3];
    const float g4 = sGs[j4], b4 = sBs[j4];
    const float g5 = sGs[j5], b5 = sBs[j5];
    const float g6 = sGs[j6], b6 = sBs[j6];
    const float g7 = sGs[j7], b7 = sBs[j7];
    float* cgp = CG + base + (size_t)pp * 128 + k;
    float* cbp = CB + base + (size_t)pp * 128 + k;
    cgp[0*128] = cg; cbp[0*128] = cb; cg = fmaf(g0, w0, cg); cb = fmaf(b0, w0, cb);
    cgp[1*128] = cg; cbp[1*128] = cb; cg = fmaf(g1, w1, cg); cb = fmaf(b1, w1, cb);
    cgp[2*128] = cg; cbp[2*128] = cb; cg = fmaf(g2, w2, cg); cb = fmaf(b2, w2, cb);
    cgp[3*128] = cg; cbp[3*128] = cb; cg = fmaf(g3, w3, cg); cb = fmaf(b3, w3, cb);
    cgp[4*128] = cg; cbp[4*128] = cb; cg = fmaf(g4, w4, cg); cb = fmaf(b4, w4, cb);
    cgp[5*128] = cg; cbp[5*128] = cb; cg = fmaf(g5, w5, cg); cb = fmaf(b5, w5, cb);
    cgp[6*128] = cg; cbp[6*128] = cb; cg = fmaf(g6, w6, cg); cb = fmaf(b6, w6, cb);
    cgp[7*128] = cg; cbp[7*128] = cb; cg = fmaf(g7, w7, cg); cb = fmaf(b7, w7, cb);
  }
  if (g == 3) {
    CG[base + (size_t)128 * 128 + k] = cg;   // prefix 128 (all crossed)
    CB[base + (size_t)128 * 128 + k] = cb;
  }

  // per-layer epilogue + affine constants
  if (t == 0) {
    meta[16 + l*4 + 0] = expf(lsf[l*2 + 0]);
    meta[16 + l*4 + 1] = expf(lsf[l*2 + 1]);
    meta[16 + l*4 + 2] = fc3_b[l*2 + 0];
    meta[16 + l*4 + 3] = fc3_b[l*2 + 1];

    const float sx = an_scale[l*2+0], sy = an_scale[l*2+1];
    const float bx = an_bias[l*2+0],  by = an_bias[l*2+1];
    const float* cw = conv_w + l*4;
    const float m00 = cw[0]/sx, m01 = cw[1]/sy;
    const float m10 = cw[2]/sx, m11 = cw[3]/sy;
    meta[64 + l*8 + 0] = m00;
    meta[64 + l*8 + 1] = m01;
    meta[64 + l*8 + 2] = m10;
    meta[64 + l*8 + 3] = m11;
    meta[64 + l*8 + 4] = -(m00*bx + m01*by);
    meta[64 + l*8 + 5] = -(m10*bx + m11*by);
  }
  if (l == 0 && t == 0) {
    float cst = 0.0f;
    for (int i = 0; i < kDepth; ++i) {
      cst -= logf(fabsf(an_scale[i*2+0]));
      cst -= logf(fabsf(an_scale[i*2+1]));
      const float* cw = conv_w + i * 4;
      float det = cw[0]*cw[3] - cw[1]*cw[2];
      cst += logf(fabsf(det));   // slogdet(conv)[1]
    }
    meta[0] = cst;
  }
}

// ---------------- table: p hoisted to once-per-node, then 4 lanes/node ----------------
__global__ __launch_bounds__(256) void table_kernel(
    const float* __restrict__ an2_scale,
    const float* __restrict__ fc3_w,
    const float* __restrict__ meta, const float* __restrict__ kv,
    const float* __restrict__ CG, const float* __restrict__ CB,
    int tabN, float4* __restrict__ tab)
{
  __shared__ float sKz[128], sKw[128], sKv[128];
  __shared__ int   sP[64];

  const int bpl   = tabN >> 6;               // 64 nodes per block
  const int l     = blockIdx.x / bpl;
  const int node0 = (blockIdx.x % bpl) * 64;
  const int t     = threadIdx.x;
  const float dv  = (kVMax - kVMin) / (float)(tabN - 1);

  if (t < 128) {
    const float si = 1.0f / an2_scale[l*kWidth + t];
    sKz[t] = fc3_w[l*2*kWidth + t] * si;
    sKw[t] = fc3_w[l*2*kWidth + kWidth + t] * si;
    sKv[t] = kv[l*128 + t];
  }
  __syncthreads();

  // phase 1: prefix index once per node (threads 0..63)
  if (t < 64) {
    const float v = kVMin + dv * (float)(node0 + t);
    int p = 0;
    const float4* kv4 = (const float4*)sKv;
#pragma unroll
    for (int m = 0; m < 32; ++m) {
      float4 K = kv4[m];                     // broadcast (lane-uniform addr)
      p += (K.x < v) + (K.y < v) + (K.z < v) + (K.w < v);
    }
    sP[t] = p;
  }
  __syncthreads();

  // phase 2: node = t>>2, kq = t&3 owns 32 k (8 float4 chunks)
  const int node = t >> 2, kq = t & 3;
  const int p = sP[node];
  const float v = kVMin + dv * (float)(node0 + node);

  const float4* cg4 = (const float4*)(CG + ((size_t)l*129 + p) * 128 + kq*32);
  const float4* cb4 = (const float4*)(CB + ((size_t)l*129 + p) * 128 + kq*32);
  const float4* kz4 = (const float4*)sKz + kq*8;
  const float4* kw4 = (const float4*)sKw + kq*8;

  float o0 = 0.f, o1 = 0.f, p0 = 0.f, p1 = 0.f;
#pragma unroll
  for (int c = 0; c < 8; ++c) {
    float4 G = cg4[c], B = cb4[c], Z = kz4[c], W = kw4[c];
    float raw, h, dd;
    raw = fmaf(v, G.x, B.x); h = fmaxf(raw, 0.f); dd = (raw > 0.f) ? G.x : 0.f;
    o0 = fmaf(h, Z.x, o0); o1 = fmaf(h, W.x, o1); p0 = fmaf(dd, Z.x, p0); p1 = fmaf(dd, W.x, p1);
    raw = fmaf(v, G.y, B.y); h = fmaxf(raw, 0.f); dd = (raw > 0.f) ? G.y : 0.f;
    o0 = fmaf(h, Z.y, o0); o1 = fmaf(h, W.y, o1); p0 = fmaf(dd, Z.y, p0); p1 = fmaf(dd, W.y, p1);
    raw = fmaf(v, G.z, B.z); h = fmaxf(raw, 0.f); dd = (raw > 0.f) ? G.z : 0.f;
    o0 = fmaf(h, Z.z, o0); o1 = fmaf(h, W.z, o1); p0 = fmaf(dd, Z.z, p0); p1 = fmaf(dd, W.z, p1);
    raw = fmaf(v, G.w, B.w); h = fmaxf(raw, 0.f); dd = (raw > 0.f) ? G.w : 0.f;
    o0 = fmaf(h, Z.w, o0); o1 = fmaf(h, W.w, o1); p0 = fmaf(dd, Z.w, p0); p1 = fmaf(dd, W.w, p1);
  }

  // reduce over the 4 kq lanes (adjacent in-wave)
  o0 += __shfl_xor(o0, 1); o0 += __shfl_xor(o0, 2);
  o1 += __shfl_xor(o1, 1); o1 += __shfl_xor(o1, 2);
  p0 += __shfl_xor(p0, 1); p0 += __shfl_xor(p0, 2);
  p1 += __shfl_xor(p1, 1); p1 += __shfl_xor(p1, 2);

  if (kq == 0) {
    const float E0  = meta[16 + l*4 + 0];
    const float E1  = meta[16 + l*4 + 1];
    const float b30 = meta[16 + l*4 + 2];
    const float b31 = meta[16 + l*4 + 3];
    tab[(size_t)l * tabN + node0 + node] =
        make_float4((o0 + b30) * E0, p0 * E0, (o1 + b31) * E1, p1 * E1);
  }
}

// bf16 round-to-nearest-even pack of two floats
__device__ __forceinline__ unsigned int pack_bf16(float a, float b) {
  unsigned int ua = __float_as_uint(a);
  unsigned int ub = __float_as_uint(b);
  ua = (ua + 0x7FFFu + ((ua >> 16) & 1u)) >> 16;
  ub = (ub + 0x7FFFu + ((ub >> 16) & 1u)) >> 16;
  return ua | (ub << 16);
}

// ---------------- main: whole table in LDS, 2 blocks/CU, 2 chains ----------------
__global__ __launch_bounds__(1024) void flow_apply_kernel(
    const float* __restrict__ x,
    const float4* __restrict__ tab, const float* __restrict__ meta,
    int tabN,
    float* __restrict__ out_z, float* __restrict__ out_ld, int n)
{
  __shared__ float2       sTU[kDepth * 512];   // (t, u)      40 KB
  __shared__ unsigned int sPK[kDepth * 512];   // bf16 dt,du  20 KB

  const int t = threadIdx.x;
  const int base = blockIdx.x * 2048;

  // stage all layers once (coalesced), convert to split/compressed form
  for (int j = t; j < kDepth * tabN; j += 1024) {
    float4 e = tab[j];
    sTU[j] = make_float2(e.x, e.z);
    sPK[j] = pack_bf16(e.y, e.w);
  }

  const int s0 = base + t;
  const int s1 = base + 1024 + t;
  const bool ok0 = s0 < n, ok1 = s1 < n;
  float2 z0 = ok0 ? reinterpret_cast<const float2*>(x)[s0] : make_float2(0.f, 0.f);
  float2 z1 = ok1 ? reinterpret_cast<const float2*>(x)[s1] : make_float2(0.f, 0.f);
  const float ldc = meta[0];
  float ld0 = ldc, ld1 = ldc;

  const float dv = (kVMax - kVMin) / (float)(tabN - 1);
  const float inv_dv = (float)(tabN - 1) / (kVMax - kVMin);
  const float offv = -kVMin * inv_dv;
  const float qmax = (float)(tabN - 1);
  constexpr float kLog2e = 1.44269504088896340736f;
  constexpr float kLn2   = 0.69314718055994530942f;

  __syncthreads();                           // table ready; no more barriers

#pragma unroll 1
  for (int i = 0; i < kDepth; ++i) {
    const float m00 = meta[64 + i*8 + 0], m01 = meta[64 + i*8 + 1];
    const float m10 = meta[64 + i*8 + 2], m11 = meta[64 + i*8 + 3];
    const float q0  = meta[64 + i*8 + 4], q1  = meta[64 + i*8 + 5];
    const float2* tu = sTU + i * tabN;
    const unsigned int* pk = sPK + i * tabN;

#pragma unroll
    for (int c = 0; c < 2; ++c) {
      float2& z  = c ? z1 : z0;
      float&  ld = c ? ld1 : ld0;
      const float na = fmaf(m00, z.x, fmaf(m01, z.y, q0));
      const float nb = fmaf(m10, z.x, fmaf(m11, z.y, q1));
      float xq = fmaf(nb, inv_dv, offv);
      xq = fminf(fmaxf(xq, 0.0f), qmax);
      const int qn = (int)(xq + 0.5f);       // nearest node, <= tabN-1
      const float2 e = tu[qn];
      const unsigned int d = pk[qn];
      const float dt = __uint_as_float(d << 16);
      const float du = __uint_as_float(d & 0xFFFF0000u);
      const float vn = fmaf((float)qn, dv, kVMin);
      const float f = nb - vn;
      const float tt = fmaf(f, dt, e.x);     // tangent line (exact unless
      const float uu = fmaf(f, du, e.y);     //  kink in the half-cell)
      // sigmoid / log-sigmoid of arg = uu + 2 via native exp2/log2/rcp
      const float arg = uu + 2.0f;
      const float ev = __builtin_amdgcn_exp2f(arg * -kLog2e);
      const float den = 1.0f + ev;
      const float s = __builtin_amdgcn_rcpf(den);
      ld = fmaf(-kLn2, __builtin_amdgcn_logf(den), ld);
      z.x = fmaf(s, na, tt);
      z.y = nb;
    }
  }

  if (ok0) {
    reinterpret_cast<float2*>(out_z)[s0] = z0;
    out_ld[s0] = ld0;
  }
  if (ok1) {
    reinterpret_cast<float2*>(out_z)[s1] = z1;
    out_ld[s1] = ld1;
  }
}

extern "C" void kernel_launch(void* const* d_in, const int* in_sizes, int n_in,
                              void* d_out, int out_size, void* d_ws, size_t ws_size,
                              hipStream_t stream) {
  const float* x         = (const float*)d_in[0];
  const float* an_scale  = (const float*)d_in[1];
  const float* an_bias   = (const float*)d_in[2];
  const float* conv_w    = (const float*)d_in[3];
  const float* fc1_w     = (const float*)d_in[4];
  const float* fc1_b     = (const float*)d_in[5];
  const float* an1_scale = (const float*)d_in[6];
  const float* an1_bias  = (const float*)d_in[7];
  const float* fc2_w     = (const float*)d_in[8];
  const float* fc2_b     = (const float*)d_in[9];
  const float* an2_scale = (const float*)d_in[10];
  const float* an2_bias  = (const float*)d_in[11];
  const float* fc3_w     = (const float*)d_in[12];
  const float* fc3_b     = (const float*)d_in[13];
  const float* lsf       = (const float*)d_in[14];

  const int n = in_sizes[0] / 2;

  // ws: [meta 256f][kv 1280f][CG 10*129*128 f][CB same][tab]
  const size_t metaF = 256, kvF = (size_t)kDepth * 128;
  const size_t cF = (size_t)kDepth * 129 * 128;
  const size_t headF = metaF + kvF + 2 * cF;
  int tabN = 512;
  while (tabN > 128 &&
         headF * 4 + (size_t)kDepth * tabN * sizeof(float4) > ws_size) {
    tabN >>= 1;
  }
  float* meta = (float*)d_ws;
  float* kv   = meta + metaF;
  float* CG   = kv + kvF;
  float* CB   = CG + cF;
  float4* tab = (float4*)(CB + cF);

  prep_kernel<<<kDepth, 512, 0, stream>>>(
      an_scale, an_bias, conv_w, fc1_w, fc1_b, an1_scale, an1_bias,
      fc2_w, fc2_b, an2_scale, an2_bias, fc3_b, lsf,
      meta, kv, CG, CB);

  table_kernel<<<kDepth * (tabN / 64), 256, 0, stream>>>(
      an2_scale, fc3_w, meta, kv, CG, CB, tabN, tab);

  const int blocks = (n + 2047) / 2048;
  flow_apply_kernel<<<blocks, 1024, 0, stream>>>(
      x, tab, meta, tabN, (float*)d_out, (float*)d_out + (size_t)2 * n, n);
}

// Round 26
// 45.669 us; speedup vs baseline: 1.0085x; 1.0085x over previous
//
#include <hip/hip_runtime.h>
#include <math.h>

// FlowLevel: DIM=2, half=1 -> per-layer coupling depends on scalar v = z_b.
// t(v) and u(v) (pre-sigmoid) are piecewise-LINEAR in v (ReLU MLP).
// Tabulate (t, dt/dv, u, du/dv) per node; apply uses the NEAREST node's
// tangent line (exact unless a kink falls in the half-cell).
//
// v23: prep distributed across 40 blocks (one per layer x 32-row p-group),
// using r25's verified direct-base formula ([g<0](g,b) + [rank<p0](gs,bs));
// each block sweeps only 32 rows -> block wall ~5us, all wall-parallel.
// The 30-logf single-lane logdet tail is distributed per layer into
// meta[144+l]; apply sums 10 floats in fixed order. table/apply = r23.

constexpr int kDepth = 10;
constexpr int kWidth = 128;
constexpr float kVMin = -24.0f;
constexpr float kVMax =  24.0f;

// ---------------- prep: block = (layer, p-group of 32 prefix rows) ----------------
__global__ __launch_bounds__(256) void prep_kernel(
    const float* __restrict__ an_scale, const float* __restrict__ an_bias,
    const float* __restrict__ conv_w,
    const float* __restrict__ fc1_w, const float* __restrict__ fc1_b,
    const float* __restrict__ an1_scale, const float* __restrict__ an1_bias,
    const float* __restrict__ fc2_w, const float* __restrict__ fc2_b,
    const float* __restrict__ an2_scale, const float* __restrict__ an2_bias,
    const float* __restrict__ fc3_b, const float* __restrict__ lsf,
    float* __restrict__ meta, float* __restrict__ kv,
    float* __restrict__ CG, float* __restrict__ CB)
{
  __shared__ float sWT[128 * 129];           // transposed weights [j][k], padded
  __shared__ float sVs[128], sG[128], sB[128];
  __shared__ float sGs[128], sBs[128];       // sig*g, sig*b (sweep deltas)
  __shared__ int   sOrd[128], sRank[128];

  const int l   = blockIdx.x >> 2;           // layer
  const int grp = blockIdx.x & 3;            // p-group: rows grp*32..grp*32+31
  const int t   = threadIdx.x;               // 0..255
  const int p0  = grp * 32;
  const float* wl = fc2_w + (size_t)l * kWidth * kWidth;

  // transpose fc2_w into sWT[j][k] -- all 256 threads, coalesced reads
#pragma unroll 8
  for (int fi = t; fi < 128 * 128; fi += 256) {
    const int k = fi >> 7, j = fi & 127;
    sWT[j * 129 + k] = wl[fi];               // sWT[j][k] = w_kj
  }

  // per-j gate params and kink position
  if (t < 128) {
    const float s1 = an1_scale[l*kWidth + t];
    const float g = fc1_w[l*kWidth + t] / s1;
    const float b = (fc1_b[l*kWidth + t] - an1_bias[l*kWidth + t]) / s1;
    float vs, sg;
    if (g > 0.0f)      { vs = -b / g; sg =  1.0f; }
    else if (g < 0.0f) { vs = -b / g; sg = -1.0f; }
    else               { vs = (b > 0.0f) ? -1e30f : 1e30f; sg = (b > 0.0f) ? 1.0f : 0.0f; }
    sG[t] = g; sB[t] = b; sVs[t] = vs;
    sGs[t] = sg * g; sBs[t] = sg * b;
  }
  __syncthreads();

  // stable rank sort by kink position (redundant per group, deterministic)
  if (t < 128) {
    const float my = sVs[t];
    int r = 0;
    const float4* vs4 = (const float4*)sVs;
#pragma unroll
    for (int i4 = 0; i4 < 32; ++i4) {
      float4 o = vs4[i4];
      const int ib = i4 * 4;
      r += (o.x < my) || (o.x == my && ib + 0 < t);
      r += (o.y < my) || (o.y == my && ib + 1 < t);
      r += (o.z < my) || (o.z == my && ib + 2 < t);
      r += (o.w < my) || (o.w == my && ib + 3 < t);
    }
    sOrd[r] = t;
    sRank[t] = r;
  }
  __syncthreads();

  if (grp == 0 && t < 128) kv[l*128 + t] = sVs[sOrd[t]];

  if (t < 128) {
    const int k = t;                         // owned output column

    // starting state at prefix p0 (verified in r25):
    // contribution_j = [g_j<0](g_j,b_j) + [rank_j<p0](sGs_j,sBs_j)
    float cg = 0.0f;
    float cb = fc2_b[l*kWidth + k] - an2_bias[l*kWidth + k];
#pragma unroll 8
    for (int j = 0; j < 128; ++j) {
      const float w  = sWT[j * 129 + k];
      const float gj = sG[j];
      float ca = (gj < 0.0f) ? gj    : 0.0f;
      float cc = (gj < 0.0f) ? sB[j] : 0.0f;
      if (sRank[j] < p0) { ca += sGs[j]; cc += sBs[j]; }
      cg = fmaf(ca, w, cg);
      cb = fmaf(cc, w, cb);
    }

    // sweep this group's 32 rows in 4 chunks of 8 (LDS reads pipelined)
    const size_t base = (size_t)l * 129 * 128;
#pragma unroll 1
    for (int c = 0; c < 4; ++c) {
      const int pp = p0 + c * 8;
      const int j0 = sOrd[pp + 0], j1 = sOrd[pp + 1];
      const int j2 = sOrd[pp + 2], j3 = sOrd[pp + 3];
      const int j4 = sOrd[pp + 4], j5 = sOrd[pp + 5];
      const int j6 = sOrd[pp + 6], j7 = sOrd[pp + 7];
      const float w0 = sWT[j0 * 129 + k], w1 = sWT[j1 * 129 + k];
      const float w2 = sWT[j2 * 129 + k], w3 = sWT[j3 * 129 + k];
      const float w4 = sWT[j4 * 129 + k], w5 = sWT[j5 * 129 + k];
      const float w6 = sWT[j6 * 129 + k], w7 = sWT[j7 * 129 + k];
      const float g0 = sGs[j0], b0 = sBs[j0];
      const float g1 = sGs[j1], b1 = sBs[j1];
      const float g2 = sGs[j2], b2 = sBs[j2];
      const float g3 = sGs[j3], b3 = sBs[j3];
      const float g4 = sGs[j4], b4 = sBs[j4];
      const float g5 = sGs[j5], b5 = sBs[j5];
      const float g6 = sGs[j6], b6 = sBs[j6];
      const float g7 = sGs[j7], b7 = sBs[j7];
      float* cgp = CG + base + (size_t)pp * 128 + k;
      float* cbp = CB + base + (size_t)pp * 128 + k;
      cgp[0*128] = cg; cbp[0*128] = cb; cg = fmaf(g0, w0, cg); cb = fmaf(b0, w0, cb);
      cgp[1*128] = cg; cbp[1*128] = cb; cg = fmaf(g1, w1, cg); cb = fmaf(b1, w1, cb);
      cgp[2*128] = cg; cbp[2*128] = cb; cg = fmaf(g2, w2, cg); cb = fmaf(b2, w2, cb);
      cgp[3*128] = cg; cbp[3*128] = cb; cg = fmaf(g3, w3, cg); cb = fmaf(b3, w3, cb);
      cgp[4*128] = cg; cbp[4*128] = cb; cg = fmaf(g4, w4, cg); cb = fmaf(b4, w4, cb);
      cgp[5*128] = cg; cbp[5*128] = cb; cg = fmaf(g5, w5, cg); cb = fmaf(b5, w5, cb);
      cgp[6*128] = cg; cbp[6*128] = cb; cg = fmaf(g6, w6, cg); cb = fmaf(b6, w6, cb);
      cgp[7*128] = cg; cbp[7*128] = cb; cg = fmaf(g7, w7, cg); cb = fmaf(b7, w7, cb);
    }
    if (grp == 3) {
      CG[base + (size_t)128 * 128 + k] = cg; // prefix 128 (all crossed)
      CB[base + (size_t)128 * 128 + k] = cb;
    }
  }

  // per-layer epilogue + affine constants + per-layer logdet partial
  if (grp == 0 && t == 0) {
    meta[16 + l*4 + 0] = expf(lsf[l*2 + 0]);
    meta[16 + l*4 + 1] = expf(lsf[l*2 + 1]);
    meta[16 + l*4 + 2] = fc3_b[l*2 + 0];
    meta[16 + l*4 + 3] = fc3_b[l*2 + 1];

    const float sx = an_scale[l*2+0], sy = an_scale[l*2+1];
    const float bx = an_bias[l*2+0],  by = an_bias[l*2+1];
    const float* cw = conv_w + l*4;
    const float m00 = cw[0]/sx, m01 = cw[1]/sy;
    const float m10 = cw[2]/sx, m11 = cw[3]/sy;
    meta[64 + l*8 + 0] = m00;
    meta[64 + l*8 + 1] = m01;
    meta[64 + l*8 + 2] = m10;
    meta[64 + l*8 + 3] = m11;
    meta[64 + l*8 + 4] = -(m00*bx + m01*by);
    meta[64 + l*8 + 5] = -(m10*bx + m11*by);

    const float det = cw[0]*cw[3] - cw[1]*cw[2];
    meta[144 + l] = logf(fabsf(det)) - logf(fabsf(sx)) - logf(fabsf(sy));
  }
}

// ---------------- table: p hoisted to once-per-node, then 4 lanes/node ----------------
__global__ __launch_bounds__(256) void table_kernel(
    const float* __restrict__ an2_scale,
    const float* __restrict__ fc3_w,
    const float* __restrict__ meta, const float* __restrict__ kv,
    const float* __restrict__ CG, const float* __restrict__ CB,
    int tabN, float4* __restrict__ tab)
{
  __shared__ float sKz[128], sKw[128], sKv[128];
  __shared__ int   sP[64];

  const int bpl   = tabN >> 6;               // 64 nodes per block
  const int l     = blockIdx.x / bpl;
  const int node0 = (blockIdx.x % bpl) * 64;
  const int t     = threadIdx.x;
  const float dv  = (kVMax - kVMin) / (float)(tabN - 1);

  if (t < 128) {
    const float si = 1.0f / an2_scale[l*kWidth + t];
    sKz[t] = fc3_w[l*2*kWidth + t] * si;
    sKw[t] = fc3_w[l*2*kWidth + kWidth + t] * si;
    sKv[t] = kv[l*128 + t];
  }
  __syncthreads();

  // phase 1: prefix index once per node (threads 0..63)
  if (t < 64) {
    const float v = kVMin + dv * (float)(node0 + t);
    int p = 0;
    const float4* kv4 = (const float4*)sKv;
#pragma unroll
    for (int m = 0; m < 32; ++m) {
      float4 K = kv4[m];                     // broadcast (lane-uniform addr)
      p += (K.x < v) + (K.y < v) + (K.z < v) + (K.w < v);
    }
    sP[t] = p;
  }
  __syncthreads();

  // phase 2: node = t>>2, kq = t&3 owns 32 k (8 float4 chunks)
  const int node = t >> 2, kq = t & 3;
  const int p = sP[node];
  const float v = kVMin + dv * (float)(node0 + node);

  const float4* cg4 = (const float4*)(CG + ((size_t)l*129 + p) * 128 + kq*32);
  const float4* cb4 = (const float4*)(CB + ((size_t)l*129 + p) * 128 + kq*32);
  const float4* kz4 = (const float4*)sKz + kq*8;
  const float4* kw4 = (const float4*)sKw + kq*8;

  float o0 = 0.f, o1 = 0.f, p0 = 0.f, p1 = 0.f;
#pragma unroll
  for (int c = 0; c < 8; ++c) {
    float4 G = cg4[c], B = cb4[c], Z = kz4[c], W = kw4[c];
    float raw, h, dd;
    raw = fmaf(v, G.x, B.x); h = fmaxf(raw, 0.f); dd = (raw > 0.f) ? G.x : 0.f;
    o0 = fmaf(h, Z.x, o0); o1 = fmaf(h, W.x, o1); p0 = fmaf(dd, Z.x, p0); p1 = fmaf(dd, W.x, p1);
    raw = fmaf(v, G.y, B.y); h = fmaxf(raw, 0.f); dd = (raw > 0.f) ? G.y : 0.f;
    o0 = fmaf(h, Z.y, o0); o1 = fmaf(h, W.y, o1); p0 = fmaf(dd, Z.y, p0); p1 = fmaf(dd, W.y, p1);
    raw = fmaf(v, G.z, B.z); h = fmaxf(raw, 0.f); dd = (raw > 0.f) ? G.z : 0.f;
    o0 = fmaf(h, Z.z, o0); o1 = fmaf(h, W.z, o1); p0 = fmaf(dd, Z.z, p0); p1 = fmaf(dd, W.z, p1);
    raw = fmaf(v, G.w, B.w); h = fmaxf(raw, 0.f); dd = (raw > 0.f) ? G.w : 0.f;
    o0 = fmaf(h, Z.w, o0); o1 = fmaf(h, W.w, o1); p0 = fmaf(dd, Z.w, p0); p1 = fmaf(dd, W.w, p1);
  }

  // reduce over the 4 kq lanes (adjacent in-wave)
  o0 += __shfl_xor(o0, 1); o0 += __shfl_xor(o0, 2);
  o1 += __shfl_xor(o1, 1); o1 += __shfl_xor(o1, 2);
  p0 += __shfl_xor(p0, 1); p0 += __shfl_xor(p0, 2);
  p1 += __shfl_xor(p1, 1); p1 += __shfl_xor(p1, 2);

  if (kq == 0) {
    const float E0  = meta[16 + l*4 + 0];
    const float E1  = meta[16 + l*4 + 1];
    const float b30 = meta[16 + l*4 + 2];
    const float b31 = meta[16 + l*4 + 3];
    tab[(size_t)l * tabN + node0 + node] =
        make_float4((o0 + b30) * E0, p0 * E0, (o1 + b31) * E1, p1 * E1);
  }
}

// bf16 round-to-nearest-even pack of two floats
__device__ __forceinline__ unsigned int pack_bf16(float a, float b) {
  unsigned int ua = __float_as_uint(a);
  unsigned int ub = __float_as_uint(b);
  ua = (ua + 0x7FFFu + ((ua >> 16) & 1u)) >> 16;
  ub = (ub + 0x7FFFu + ((ub >> 16) & 1u)) >> 16;
  return ua | (ub << 16);
}

// ---------------- main: whole table in LDS, 2 blocks/CU, 2 chains ----------------
__global__ __launch_bounds__(1024) void flow_apply_kernel(
    const float* __restrict__ x,
    const float4* __restrict__ tab, const float* __restrict__ meta,
    int tabN,
    float* __restrict__ out_z, float* __restrict__ out_ld, int n)
{
  __shared__ float2       sTU[kDepth * 512];   // (t, u)      40 KB
  __shared__ unsigned int sPK[kDepth * 512];   // bf16 dt,du  20 KB

  const int t = threadIdx.x;
  const int base = blockIdx.x * 2048;

  // stage all layers once (coalesced), convert to split/compressed form
  for (int j = t; j < kDepth * tabN; j += 1024) {
    float4 e = tab[j];
    sTU[j] = make_float2(e.x, e.z);
    sPK[j] = pack_bf16(e.y, e.w);
  }

  const int s0 = base + t;
  const int s1 = base + 1024 + t;
  const bool ok0 = s0 < n, ok1 = s1 < n;
  float2 z0 = ok0 ? reinterpret_cast<const float2*>(x)[s0] : make_float2(0.f, 0.f);
  float2 z1 = ok1 ? reinterpret_cast<const float2*>(x)[s1] : make_float2(0.f, 0.f);

  // logdet constant: fixed-order sum of per-layer partials (deterministic)
  float ldc = 0.0f;
#pragma unroll
  for (int i = 0; i < kDepth; ++i) ldc += meta[144 + i];
  float ld0 = ldc, ld1 = ldc;

  const float dv = (kVMax - kVMin) / (float)(tabN - 1);
  const float inv_dv = (float)(tabN - 1) / (kVMax - kVMin);
  const float offv = -kVMin * inv_dv;
  const float qmax = (float)(tabN - 1);
  constexpr float kLog2e = 1.44269504088896340736f;
  constexpr float kLn2   = 0.69314718055994530942f;

  __syncthreads();                           // table ready; no more barriers

#pragma unroll 1
  for (int i = 0; i < kDepth; ++i) {
    const float m00 = meta[64 + i*8 + 0], m01 = meta[64 + i*8 + 1];
    const float m10 = meta[64 + i*8 + 2], m11 = meta[64 + i*8 + 3];
    const float q0  = meta[64 + i*8 + 4], q1  = meta[64 + i*8 + 5];
    const float2* tu = sTU + i * tabN;
    const unsigned int* pk = sPK + i * tabN;

#pragma unroll
    for (int c = 0; c < 2; ++c) {
      float2& z  = c ? z1 : z0;
      float&  ld = c ? ld1 : ld0;
      const float na = fmaf(m00, z.x, fmaf(m01, z.y, q0));
      const float nb = fmaf(m10, z.x, fmaf(m11, z.y, q1));
      float xq = fmaf(nb, inv_dv, offv);
      xq = fminf(fmaxf(xq, 0.0f), qmax);
      const int qn = (int)(xq + 0.5f);       // nearest node, <= tabN-1
      const float2 e = tu[qn];
      const unsigned int d = pk[qn];
      const float dt = __uint_as_float(d << 16);
      const float du = __uint_as_float(d & 0xFFFF0000u);
      const float vn = fmaf((float)qn, dv, kVMin);
      const float f = nb - vn;
      const float tt = fmaf(f, dt, e.x);     // tangent line (exact unless
      const float uu = fmaf(f, du, e.y);     //  kink in the half-cell)
      // sigmoid / log-sigmoid of arg = uu + 2 via native exp2/log2/rcp
      const float arg = uu + 2.0f;
      const float ev = __builtin_amdgcn_exp2f(arg * -kLog2e);
      const float den = 1.0f + ev;
      const float s = __builtin_amdgcn_rcpf(den);
      ld = fmaf(-kLn2, __builtin_amdgcn_logf(den), ld);
      z.x = fmaf(s, na, tt);
      z.y = nb;
    }
  }

  if (ok0) {
    reinterpret_cast<float2*>(out_z)[s0] = z0;
    out_ld[s0] = ld0;
  }
  if (ok1) {
    reinterpret_cast<float2*>(out_z)[s1] = z1;
    out_ld[s1] = ld1;
  }
}

extern "C" void kernel_launch(void* const* d_in, const int* in_sizes, int n_in,
                              void* d_out, int out_size, void* d_ws, size_t ws_size,
                              hipStream_t stream) {
  const float* x         = (const float*)d_in[0];
  const float* an_scale  = (const float*)d_in[1];
  const float* an_bias   = (const float*)d_in[2];
  const float* conv_w    = (const float*)d_in[3];
  const float* fc1_w     = (const float*)d_in[4];
  const float* fc1_b     = (const float*)d_in[5];
  const float* an1_scale = (const float*)d_in[6];
  const float* an1_bias  = (const float*)d_in[7];
  const float* fc2_w     = (const float*)d_in[8];
  const float* fc2_b     = (const float*)d_in[9];
  const float* an2_scale = (const float*)d_in[10];
  const float* an2_bias  = (const float*)d_in[11];
  const float* fc3_w     = (const float*)d_in[12];
  const float* fc3_b     = (const float*)d_in[13];
  const float* lsf       = (const float*)d_in[14];

  const int n = in_sizes[0] / 2;

  // ws: [meta 256f][kv 1280f][CG 10*129*128 f][CB same][tab]
  const size_t metaF = 256, kvF = (size_t)kDepth * 128;
  const size_t cF = (size_t)kDepth * 129 * 128;
  const size_t headF = metaF + kvF + 2 * cF;
  int tabN = 512;
  while (tabN > 128 &&
         headF * 4 + (size_t)kDepth * tabN * sizeof(float4) > ws_size) {
    tabN >>= 1;
  }
  float* meta = (float*)d_ws;
  float* kv   = meta + metaF;
  float* CG   = kv + kvF;
  float* CB   = CG + cF;
  float4* tab = (float4*)(CB + cF);

  prep_kernel<<<kDepth * 4, 256, 0, stream>>>(
      an_scale, an_bias, conv_w, fc1_w, fc1_b, an1_scale, an1_bias,
      fc2_w, fc2_b, an2_scale, an2_bias, fc3_b, lsf,
      meta, kv, CG, CB);

  table_kernel<<<kDepth * (tabN / 64), 256, 0, stream>>>(
      an2_scale, fc3_w, meta, kv, CG, CB, tabN, tab);

  const int blocks = (n + 2047) / 2048;
  flow_apply_kernel<<<blocks, 1024, 0, stream>>>(
      x, tab, meta, tabN, (float*)d_out, (float*)d_out + (size_t)2 * n, n);
}